// Round 8
// baseline (409.466 us; speedup 1.0000x reference)
//
#include <hip/hip_runtime.h>
#include <math.h>

#define BB 4
#define LL 2048
#define DD 512
#define CC 64      // chunk length
#define NC 32      // number of chunks
#define VB 8       // v-columns owned per workgroup
#define EPSF 1e-5f

typedef unsigned int u32;
typedef unsigned short u16;
typedef __attribute__((ext_vector_type(4))) u32 u32x4;
typedef __attribute__((ext_vector_type(4))) float f32x4;
typedef __attribute__((ext_vector_type(8))) __bf16 bf16x8;

__device__ __forceinline__ u16 f2bf(float f) {           // native RNE cvt
  return __builtin_bit_cast(u16, (__bf16)f);
}
__device__ __forceinline__ int sx6(int s) { return (s ^ (s >> 3)) & 7; }
__device__ __forceinline__ bf16x8 ldf(const u16* p) {
  return __builtin_bit_cast(bf16x8, *(const u32x4*)p);
}
__device__ __forceinline__ bf16x8 bcv(u32x4 v) { return __builtin_bit_cast(bf16x8, v); }

__device__ __forceinline__ void gld16(u16* lds, const u16* g) {
  __builtin_amdgcn_global_load_lds(
      (const __attribute__((address_space(1))) u32*)g,
      (__attribute__((address_space(3))) u32*)lds, 16, 0, 0);
}
// barrier that drains only LDS (keeps global loads in flight)
__device__ __forceinline__ void barrier_lgkm() {
  asm volatile("s_waitcnt lgkmcnt(0)" ::: "memory");
  __builtin_amdgcn_sched_barrier(0);
  __builtin_amdgcn_s_barrier();
  __builtin_amdgcn_sched_barrier(0);
}
__device__ __forceinline__ void barrier_all() {
  asm volatile("s_waitcnt vmcnt(0) lgkmcnt(0)" ::: "memory");
  __builtin_amdgcn_sched_barrier(0);
  __builtin_amdgcn_s_barrier();
  __builtin_amdgcn_sched_barrier(0);
}

// ---------------------------------------------------------------------------
// K1: x_act = tanh(x) -> kbs bf16, pre-swizzled rows:
//     kbs[row*512 + (k ^ (sx6(row&63)<<3))]
// ---------------------------------------------------------------------------
__global__ __launch_bounds__(256) void k_tanh(const float* __restrict__ x,
                                              u16* __restrict__ kbs) {
  int row  = blockIdx.x * 4 + (threadIdx.x >> 6);
  int lane = threadIdx.x & 63;
  const float* xr = x + (size_t)row * DD + lane * 8;
  float4 a = *(const float4*)xr;
  float4 b = *(const float4*)(xr + 4);
  float v[8] = {a.x, a.y, a.z, a.w, b.x, b.y, b.z, b.w};
  u32x4 pk;
#pragma unroll
  for (int j = 0; j < 4; ++j) {
    u16 h0 = f2bf(tanhf(v[2 * j]));
    u16 h1 = f2bf(tanhf(v[2 * j + 1]));
    pk[j] = (u32)h0 | ((u32)h1 << 16);
  }
  int s = row & 63;
  int k0 = (lane * 8) ^ (sx6(s) << 3);
  *(u32x4*)(kbs + (size_t)row * DD + k0) = pk;
}

// ---------------------------------------------------------------------------
// K1b: W -> bf16 (row-major)
// ---------------------------------------------------------------------------
__global__ __launch_bounds__(256) void k_cvtW(const float* __restrict__ W,
                                              u16* __restrict__ wbb) {
  int idx = (blockIdx.x * 256 + threadIdx.x) * 8;
  float4 a = *(const float4*)(W + idx);
  float4 b = *(const float4*)(W + idx + 4);
  float v[8] = {a.x, a.y, a.z, a.w, b.x, b.y, b.z, b.w};
  u32x4 pk;
#pragma unroll
  for (int j = 0; j < 4; ++j)
    pk[j] = (u32)f2bf(v[2 * j]) | ((u32)f2bf(v[2 * j + 1]) << 16);
  *(u32x4*)(wbb + idx) = pk;
}

// ---------------------------------------------------------------------------
// K2: per-(b,chunk) prep (unchanged):
//   G = K K^T via MFMA; T = (I+A)^{-1} forward substitution (4 lanes/col).
//   Outputs (bf16): tbb = beta*T ; tcb = -beta*T[s][r]*lam^{r+1} ;
//   mtb[s][r] = lam^{s-r}G[s][r] (r<s), G[s][s] (r==s), 0 else;
//   kbt = K^T pre-swizzled: kbt[k*64 + (s ^ (sx6(k)<<3))].
// ---------------------------------------------------------------------------
__global__ __launch_bounds__(256) void k_prep2(const u16* __restrict__ kbs,
                                               const float* __restrict__ eta_p,
                                               const float* __restrict__ ll_p,
                                               u16* __restrict__ tbb,
                                               u16* __restrict__ tcb,
                                               u16* __restrict__ mtb,
                                               u16* __restrict__ kbt) {
  __shared__ __align__(16) u16 Kl[CC * DD];
  __shared__ float Gl[64 * 64];
  __shared__ float Gs[64 * 64];
  __shared__ float Tl[64 * 65];
  __shared__ float pw[72];
  int bc = blockIdx.x;
  int b = bc >> 5, c = bc & 31;
  int tid = threadIdx.x;
  int wid = tid >> 6, lane = tid & 63;
  int lo = lane & 15, hi = lane >> 4;
  float beta = *eta_p;
  float lam = 1.f / (1.f + expf(-*ll_p));
  if (tid <= 64) pw[tid] = powf(lam, (float)tid);
  for (int i = tid; i < 64 * 65; i += 256) Tl[i] = 0.f;
  const u16* Kg = kbs + (size_t)(b * LL + c * CC) * DD;
#pragma unroll
  for (int i = 0; i < 16; ++i)
    gld16(Kl + (size_t)(i * 256 + tid) * 8, Kg + (size_t)(i * 256 + tid) * 8);
  __syncthreads();
  {
    f32x4 acc[4] = {{0.f,0.f,0.f,0.f},{0.f,0.f,0.f,0.f},{0.f,0.f,0.f,0.f},{0.f,0.f,0.f,0.f}};
    int t = 16 * wid + lo;
    int mT = sx6(t) << 3;
#pragma unroll
    for (int kq = 0; kq < 16; ++kq) {
      int col = hi * 8 + kq * 32;
      bf16x8 aF = ldf(Kl + t * DD + (col ^ mT));
#pragma unroll
      for (int sb = 0; sb < 4; ++sb) {
        int s = 16 * sb + lo;
        bf16x8 bF = ldf(Kl + s * DD + (col ^ (sx6(s) << 3)));
        acc[sb] = __builtin_amdgcn_mfma_f32_16x16x32_bf16(aF, bF, acc[sb], 0, 0, 0);
      }
    }
#pragma unroll
    for (int sb = 0; sb < 4; ++sb)
#pragma unroll
      for (int r = 0; r < 4; ++r)
        Gl[(16 * wid + 4 * hi + r) * 64 + 16 * sb + lo] = acc[sb][r];
  }
  __syncthreads();
#pragma unroll
  for (int i = 0; i < 16; ++i) {
    int idx = tid + i * 256;
    int tq = idx >> 6, sq = idx & 63;
    Gs[idx] = (sq < tq) ? beta * pw[tq - sq] * Gl[idx] : 0.f;
  }
  __syncthreads();
  {
    int q = hi;
    int j = 16 * wid + lo;
    for (int t = 0; t < 64; ++t) {
      float ps = 0.f;
#pragma unroll
      for (int i = 0; i < 16; ++i) {
        int s = 16 * q + i;
        ps = fmaf(Gs[t * 64 + s], Tl[s * 65 + j], ps);
      }
      ps += __shfl_xor(ps, 16, 64);
      ps += __shfl_xor(ps, 32, 64);
      if (q == 0) Tl[t * 65 + j] = ((t == j) ? 1.f : 0.f) - ps;
    }
  }
  __syncthreads();
  u16* tb = tbb + (size_t)bc * 64 * 64;
  u16* tc = tcb + (size_t)bc * 64 * 64;
  u16* mt = mtb + (size_t)bc * 64 * 64;
#pragma unroll
  for (int i = 0; i < 16; ++i) {
    int idx = tid + i * 256;
    int s = idx >> 6, r = idx & 63;
    float tv = Tl[s * 65 + r];
    tb[idx] = f2bf(beta * tv);
    tc[idx] = f2bf(-(beta * tv * pw[r + 1]));
    mt[idx] = f2bf((r < s) ? pw[s - r] * Gl[s * 64 + r]
                           : ((r == s) ? Gl[s * 64 + r] : 0.f));
  }
  u16* ktb = kbt + (size_t)bc * CC * DD;
#pragma unroll
  for (int rr = 0; rr < 2; ++rr) {
    int k = rr * 256 + tid;
    int kbase = k & ~7, klo = k & 7;
    int mk = sx6(k) << 3;
#pragma unroll
    for (int g = 0; g < 8; ++g) {
      u32 w4[4];
#pragma unroll
      for (int p = 0; p < 4; ++p) {
        int s0 = g * 8 + 2 * p;
        u16 e0 = Kl[s0 * DD + (kbase ^ (sx6(s0) << 3)) + klo];
        u16 e1 = Kl[(s0 + 1) * DD + (kbase ^ (sx6(s0 + 1) << 3)) + klo];
        w4[p] = (u32)e0 | ((u32)e1 << 16);
      }
      *(u32x4*)(ktb + (size_t)k * 64 + ((8 * g) ^ mk)) = (u32x4){w4[0], w4[1], w4[2], w4[3]};
    }
  }
}

// ---------------------------------------------------------------------------
// K3: MFMA chunked scan, 16 waves (1024 thr) = 4 waves/SIMD, k-split 4.
//   V = W.K^T hoisted OFF the critical path: V[c+1] computed in the B-slot
//   of chunk c (Kl already holds K[c+1] there). Per chunk:
//     A(U) -> bar -> stage-write + reduce(U;V via Vp) -> bar ->
//     B(kh0) || V[c+1](all) -> bar -> C(kh1)+D(all)+prefetch -> bar
// ---------------------------------------------------------------------------
__global__ __launch_bounds__(1024, 4) void k_scan7(const u16* __restrict__ kbs,
                                                   const u16* __restrict__ kbt,
                                                   const u16* __restrict__ wbb,
                                                   const u16* __restrict__ tbb,
                                                   const u16* __restrict__ tcb,
                                                   const u16* __restrict__ mtb,
                                                   const float* __restrict__ ll_p,
                                                   float* __restrict__ y) {
  __shared__ __align__(16) u16 Kl[CC * DD];     // 64 KB
  __shared__ __align__(16) u16 Sb[16 * DD];     // 16 KB bf16 state copy
  __shared__ float Vp[4 * 16 * 68];             // 17 KB fp32 V partials
  __shared__ float Up[4 * 16 * 68];             // 17 KB fp32 U partials
  __shared__ __align__(16) u16 Vt[16 * 64];
  __shared__ __align__(16) u16 Ut[16 * 64];
  __shared__ __align__(16) u16 Wt[16 * 64];
  __shared__ __align__(16) u16 Ws[16 * 64];

  int b = blockIdx.x >> 6;
  int vb = blockIdx.x & 63;
  int v0 = vb * VB;
  int tid = threadIdx.x;
  int wid = tid >> 6, lane = tid & 63;
  int wq = wid & 3, kh = wid >> 2;      // s-quad, k-quarter
  int lo = lane & 15, hi = lane >> 4;
  int sidx = 16 * wq + lo;
  int mK = sx6(sidx) << 3;
  int mLo = sx6(lo) << 3;
  int kOff = kh * 128;

  float lam = 1.f / (1.f + expf(-*ll_p));
  float lam64 = powf(lam, 64.f);
  float csc = powf(lam, (float)(sidx + 1));
  float dsc = powf(lam, (float)(63 - sidx));

  {
    u32x4 z = {0u, 0u, 0u, 0u};
    *((u32x4*)Sb + tid) = z;                        // 1024*16B = 16KB
    if (tid < 512) {
      u16* base = (tid >> 7) == 0 ? Vt : (tid >> 7) == 1 ? Ut
                : (tid >> 7) == 2 ? Wt : Ws;
      *((u32x4*)base + (tid & 127)) = z;
    }
  }
  const u16* kb_b = kbs + (size_t)b * LL * DD;
  float* yb = y + (size_t)b * LL * DD;

  // W A-fragments (chunk-invariant, k-quarter)
  u32x4 wf[4];
#pragma unroll
  for (int kq = 0; kq < 4; ++kq)
    wf[kq] = *(const u32x4*)(wbb + (size_t)((v0 + lo) & 511) * DD + kOff + hi * 8 + kq * 32);

  // prologue: stage chunk 0, frames for chunk 0
  u32x4 sreg[4];
#pragma unroll
  for (int i = 0; i < 4; ++i)
    sreg[i] = *(const u32x4*)(kb_b + (size_t)(i * 1024 + tid) * 8);
  u32x4 kt0[2], kt1[2], tA0, tA1, tB0, tB1;
  {
    const u16* ktc = kbt + (size_t)(b * NC + 0) * CC * DD;
#pragma unroll
    for (int t = 0; t < 2; ++t) {
      int k = 16 * (2 * wid + t) + lo;
      const u16* rowp = ktc + (size_t)k * 64;
      int m = sx6(k) << 3;
      kt0[t] = *(const u32x4*)(rowp + ((8 * hi) ^ m));
      kt1[t] = *(const u32x4*)(rowp + ((8 * hi + 32) ^ m));
    }
    size_t tbase = ((size_t)(b * NC + 0) * 64 + sidx) * 64 + hi * 8;
    if (kh == 0) {
      tA0 = *(const u32x4*)(tbb + tbase);
      tA1 = *(const u32x4*)(tbb + tbase + 32);
      tB0 = *(const u32x4*)(tcb + tbase);
      tB1 = *(const u32x4*)(tcb + tbase + 32);
    } else {
      tA0 = *(const u32x4*)(mtb + tbase);
      tA1 = *(const u32x4*)(mtb + tbase + 32);
      tB0 = tA0; tB1 = tA1;
    }
  }
#pragma unroll
  for (int i = 0; i < 4; ++i)
    *(u32x4*)(Kl + (size_t)(i * 1024 + tid) * 8) = sreg[i];

  f32x4 Sa[2];
  Sa[0] = (f32x4){0.f, 0.f, 0.f, 0.f};
  Sa[1] = (f32x4){0.f, 0.f, 0.f, 0.f};
  barrier_all();

  // prologue: V[0] partials
  {
    f32x4 Va0 = {0.f,0.f,0.f,0.f}, Va1 = {0.f,0.f,0.f,0.f};
#pragma unroll
    for (int kq = 0; kq < 4; ++kq) {
      int col = kOff + hi * 8 + kq * 32;
      bf16x8 kB = ldf(Kl + sidx * DD + (col ^ mK));
      if (kq & 1) Va1 = __builtin_amdgcn_mfma_f32_16x16x32_bf16(bcv(wf[kq]), kB, Va1, 0, 0, 0);
      else        Va0 = __builtin_amdgcn_mfma_f32_16x16x32_bf16(bcv(wf[kq]), kB, Va0, 0, 0, 0);
    }
    f32x4 Va = Va0 + Va1;
#pragma unroll
    for (int r = 0; r < 4; ++r)
      Vp[(kh * 16 + 4 * hi + r) * 68 + sidx] = Va[r];
  }

  for (int c = 0; c < NC; ++c) {
    // issue stage loads for c+1
    if (c + 1 < NC) {
      const u16* src = kb_b + (size_t)(c + 1) * CC * DD;
#pragma unroll
      for (int i = 0; i < 4; ++i)
        sreg[i] = *(const u32x4*)(src + (size_t)(i * 1024 + tid) * 8);
    }
    // ---- phase A: U partials (k-quarter) ----
    {
      f32x4 Ua0 = {0.f,0.f,0.f,0.f}, Ua1 = {0.f,0.f,0.f,0.f};
#pragma unroll
      for (int kq = 0; kq < 4; ++kq) {
        int col = kOff + hi * 8 + kq * 32;
        bf16x8 kB = ldf(Kl + sidx * DD + (col ^ mK));
        bf16x8 sA = ldf(Sb + lo * DD + (col ^ mLo));
        if (kq & 1) Ua1 = __builtin_amdgcn_mfma_f32_16x16x32_bf16(sA, kB, Ua1, 0, 0, 0);
        else        Ua0 = __builtin_amdgcn_mfma_f32_16x16x32_bf16(sA, kB, Ua0, 0, 0, 0);
      }
      f32x4 Ua = Ua0 + Ua1;
#pragma unroll
      for (int r = 0; r < 4; ++r)
        Up[(kh * 16 + 4 * hi + r) * 68 + sidx] = Ua[r];
    }
    barrier_lgkm();
    // stage-write c+1 into Kl (Kl reads for chunk c all done)
    if (c + 1 < NC) {
#pragma unroll
      for (int i = 0; i < 4; ++i)
        *(u32x4*)(Kl + (size_t)(i * 1024 + tid) * 8) = sreg[i];
    }
    // ---- reduce: UaF (kh<2), VaF; Ut/Vt tiles by kh0 ----
    float UaF[4], VaF[4];
    if (kh < 2) {
#pragma unroll
      for (int r = 0; r < 4; ++r) {
        int v = 4 * hi + r;
        UaF[r] = (Up[v * 68 + sidx] + Up[(16 + v) * 68 + sidx]) +
                 (Up[(32 + v) * 68 + sidx] + Up[(48 + v) * 68 + sidx]);
        VaF[r] = (Vp[v * 68 + sidx] + Vp[(16 + v) * 68 + sidx]) +
                 (Vp[(32 + v) * 68 + sidx] + Vp[(48 + v) * 68 + sidx]);
      }
      if (kh == 0 && hi < 2) {
#pragma unroll
        for (int r = 0; r < 4; ++r) {
          int v = 4 * hi + r;
          int idx = v * 64 + (sidx ^ (sx6(v) << 3));
          Ut[idx] = f2bf(UaF[r]);
          Vt[idx] = f2bf(VaF[r]);
        }
      }
    }
    barrier_lgkm();
    // ---- B (kh0) || V[c+1] (all) ----
    if (kh == 0) {
      bf16x8 vf0 = ldf(Vt + lo * 64 + ((hi * 8) ^ mLo));
      bf16x8 vf1 = ldf(Vt + lo * 64 + ((hi * 8 + 32) ^ mLo));
      bf16x8 uf0 = ldf(Ut + lo * 64 + ((hi * 8) ^ mLo));
      bf16x8 uf1 = ldf(Ut + lo * 64 + ((hi * 8 + 32) ^ mLo));
      f32x4 Wa0 = {0.f,0.f,0.f,0.f}, Wa1 = {0.f,0.f,0.f,0.f};
      Wa0 = __builtin_amdgcn_mfma_f32_16x16x32_bf16(vf0, bcv(tA0), Wa0, 0, 0, 0);
      Wa1 = __builtin_amdgcn_mfma_f32_16x16x32_bf16(vf1, bcv(tA1), Wa1, 0, 0, 0);
      Wa0 = __builtin_amdgcn_mfma_f32_16x16x32_bf16(uf0, bcv(tB0), Wa0, 0, 0, 0);
      Wa1 = __builtin_amdgcn_mfma_f32_16x16x32_bf16(uf1, bcv(tB1), Wa1, 0, 0, 0);
      f32x4 Wa = Wa0 + Wa1;
      if (hi < 2) {
#pragma unroll
        for (int r = 0; r < 4; ++r) {
          int v = 4 * hi + r;
          int idx = v * 64 + (sidx ^ (sx6(v) << 3));
          Wt[idx] = f2bf(Wa[r]);
          Ws[idx] = f2bf(Wa[r] * dsc);
        }
      }
    }
    if (c + 1 < NC) {  // V for c+1 (Kl = K[c+1] after bar2)
      f32x4 Va0 = {0.f,0.f,0.f,0.f}, Va1 = {0.f,0.f,0.f,0.f};
#pragma unroll
      for (int kq = 0; kq < 4; ++kq) {
        int col = kOff + hi * 8 + kq * 32;
        bf16x8 kB = ldf(Kl + sidx * DD + (col ^ mK));
        if (kq & 1) Va1 = __builtin_amdgcn_mfma_f32_16x16x32_bf16(bcv(wf[kq]), kB, Va1, 0, 0, 0);
        else        Va0 = __builtin_amdgcn_mfma_f32_16x16x32_bf16(bcv(wf[kq]), kB, Va0, 0, 0, 0);
      }
      f32x4 Va = Va0 + Va1;
#pragma unroll
      for (int r = 0; r < 4; ++r)
        Vp[(kh * 16 + 4 * hi + r) * 68 + sidx] = Va[r];
    }
    barrier_lgkm();
    // ---- C (kh1) + y ----
    if (kh == 1) {
      f32x4 Oa;
#pragma unroll
      for (int r = 0; r < 4; ++r) Oa[r] = csc * UaF[r];
      bf16x8 wff0 = ldf(Wt + lo * 64 + ((hi * 8) ^ mLo));
      bf16x8 wff1 = ldf(Wt + lo * 64 + ((hi * 8 + 32) ^ mLo));
      Oa = __builtin_amdgcn_mfma_f32_16x16x32_bf16(wff0, bcv(tA0), Oa, 0, 0, 0);
      Oa = __builtin_amdgcn_mfma_f32_16x16x32_bf16(wff1, bcv(tA1), Oa, 0, 0, 0);
      if (hi < 2) {
        float4 yo = make_float4(VaF[0] + Oa[0], VaF[1] + Oa[1],
                                VaF[2] + Oa[2], VaF[3] + Oa[3]);
        *(float4*)(yb + (size_t)(c * CC + sidx) * DD + v0 + 4 * hi) = yo;
      }
    }
    // ---- D (all waves, 2 k-slices each) ----
    {
      bf16x8 ws0 = ldf(Ws + lo * 64 + ((hi * 8) ^ mLo));
      bf16x8 ws1 = ldf(Ws + lo * 64 + ((hi * 8 + 32) ^ mLo));
#pragma unroll
      for (int t = 0; t < 2; ++t) {
        f32x4 acc = Sa[t] * lam64;
        acc = __builtin_amdgcn_mfma_f32_16x16x32_bf16(ws0, bcv(kt0[t]), acc, 0, 0, 0);
        acc = __builtin_amdgcn_mfma_f32_16x16x32_bf16(ws1, bcv(kt1[t]), acc, 0, 0, 0);
        Sa[t] = acc;
      }
      if (hi < 2) {
#pragma unroll
        for (int t = 0; t < 2; ++t) {
          int kc = 16 * (2 * wid + t) + lo;
#pragma unroll
          for (int r = 0; r < 4; ++r) {
            int v = 4 * hi + r;
            Sb[v * DD + (kc ^ (sx6(v) << 3))] = f2bf(Sa[t][r]);
          }
        }
      }
    }
    // ---- prefetch frames for c+1 ----
    if (c + 1 < NC) {
      const u16* ktc = kbt + (size_t)(b * NC + c + 1) * CC * DD;
#pragma unroll
      for (int t = 0; t < 2; ++t) {
        int k = 16 * (2 * wid + t) + lo;
        const u16* rowp = ktc + (size_t)k * 64;
        int m = sx6(k) << 3;
        kt0[t] = *(const u32x4*)(rowp + ((8 * hi) ^ m));
        kt1[t] = *(const u32x4*)(rowp + ((8 * hi + 32) ^ m));
      }
      size_t tbase = ((size_t)(b * NC + c + 1) * 64 + sidx) * 64 + hi * 8;
      if (kh == 0) {
        tA0 = *(const u32x4*)(tbb + tbase);
        tA1 = *(const u32x4*)(tbb + tbase + 32);
        tB0 = *(const u32x4*)(tcb + tbase);
        tB1 = *(const u32x4*)(tcb + tbase + 32);
      } else if (kh == 1) {
        tA0 = *(const u32x4*)(mtb + tbase);
        tA1 = *(const u32x4*)(mtb + tbase + 32);
      }
    }
    barrier_lgkm();
  }
}

// ---------------------------------------------------------------------------
// K4: LayerNorm in-place on d_out.
// ---------------------------------------------------------------------------
__global__ __launch_bounds__(256) void k_ln(float* __restrict__ y,
                                            const float* __restrict__ gamma,
                                            const float* __restrict__ lbeta) {
  int row = blockIdx.x * 4 + (threadIdx.x >> 6);
  int lane = threadIdx.x & 63;
  float* yr = y + (size_t)row * DD + lane * 8;
  float4 a = *(const float4*)yr;
  float4 b = *(const float4*)(yr + 4);
  float v[8] = {a.x, a.y, a.z, a.w, b.x, b.y, b.z, b.w};
  float s = 0.f, ss = 0.f;
#pragma unroll
  for (int j = 0; j < 8; ++j) {
    s += v[j];
    ss = fmaf(v[j], v[j], ss);
  }
#pragma unroll
  for (int m = 1; m < 64; m <<= 1) {
    s += __shfl_xor(s, m, 64);
    ss += __shfl_xor(ss, m, 64);
  }
  float mu = s * (1.f / DD);
  float var = ss * (1.f / DD) - mu * mu;
  float inv = rsqrtf(var + EPSF);
  const float* gp = gamma + lane * 8;
  const float* bp = lbeta + lane * 8;
  float4 g0 = *(const float4*)gp;
  float4 g1 = *(const float4*)(gp + 4);
  float4 b0 = *(const float4*)bp;
  float4 b1 = *(const float4*)(bp + 4);
  float g[8] = {g0.x, g0.y, g0.z, g0.w, g1.x, g1.y, g1.z, g1.w};
  float bb[8] = {b0.x, b0.y, b0.z, b0.w, b1.x, b1.y, b1.z, b1.w};
#pragma unroll
  for (int j = 0; j < 8; ++j) v[j] = (v[j] - mu) * inv * g[j] + bb[j];
  *(float4*)yr = make_float4(v[0], v[1], v[2], v[3]);
  *(float4*)(yr + 4) = make_float4(v[4], v[5], v[6], v[7]);
}

// ---------------------------------------------------------------------------
extern "C" void kernel_launch(void* const* d_in, const int* in_sizes, int n_in,
                              void* d_out, int out_size, void* d_ws, size_t ws_size,
                              hipStream_t stream) {
  const float* x     = (const float*)d_in[0];
  const float* W     = (const float*)d_in[1];
  const float* eta   = (const float*)d_in[2];
  const float* ll    = (const float*)d_in[3];
  const float* gamma = (const float*)d_in[4];
  const float* lbeta = (const float*)d_in[5];
  float* out = (float*)d_out;

  // ws (u16): kbs 8MB | kbt 8MB | wbb 0.5MB | tbb/tcb/mtb 1MB each (~20.5MB)
  u16* kbs = (u16*)d_ws;
  u16* kbt = kbs + (size_t)BB * LL * DD;
  u16* wbb = kbt + (size_t)BB * LL * DD;
  u16* tbb = wbb + (size_t)DD * DD;
  u16* tcb = tbb + (size_t)BB * NC * 64 * 64;
  u16* mtb = tcb + (size_t)BB * NC * 64 * 64;

  k_tanh<<<2048, 256, 0, stream>>>(x, kbs);
  k_cvtW<<<128, 256, 0, stream>>>(W, wbb);
  k_prep2<<<BB * NC, 256, 0, stream>>>(kbs, eta, ll, tbb, tcb, mtb, kbt);
  k_scan7<<<256, 1024, 0, stream>>>(kbs, kbt, wbb, tbb, tcb, mtb, ll, out);
  k_ln<<<2048, 256, 0, stream>>>(out, gamma, lbeta);
}

// Round 9
// 173.254 us; speedup vs baseline: 2.3634x; 2.3634x over previous
//
#include <hip/hip_runtime.h>
#include <math.h>

#define BB 4
#define LL 2048
#define DD 512
#define CC 64      // chunk length
#define NC 32      // number of chunks
#define VB 8       // v-columns owned per workgroup
#define EPSF 1e-5f

typedef unsigned int u32;
typedef unsigned short u16;
typedef __attribute__((ext_vector_type(4))) u32 u32x4;
typedef __attribute__((ext_vector_type(4))) float f32x4;
typedef __attribute__((ext_vector_type(8))) __bf16 bf16x8;

__device__ __forceinline__ u16 f2bf(float f) {           // native RNE cvt
  return __builtin_bit_cast(u16, (__bf16)f);
}
__device__ __forceinline__ int sx6(int s) { return (s ^ (s >> 3)) & 7; }
__device__ __forceinline__ bf16x8 ldf(const u16* p) {
  return __builtin_bit_cast(bf16x8, *(const u32x4*)p);
}
__device__ __forceinline__ bf16x8 bcv(u32x4 v) { return __builtin_bit_cast(bf16x8, v); }

// barrier that drains only LDS (keeps global loads in flight)
__device__ __forceinline__ void barrier_lgkm() {
  asm volatile("s_waitcnt lgkmcnt(0)" ::: "memory");
  __builtin_amdgcn_sched_barrier(0);
  __builtin_amdgcn_s_barrier();
  __builtin_amdgcn_sched_barrier(0);
}
__device__ __forceinline__ void barrier_all() {
  asm volatile("s_waitcnt vmcnt(0) lgkmcnt(0)" ::: "memory");
  __builtin_amdgcn_sched_barrier(0);
  __builtin_amdgcn_s_barrier();
  __builtin_amdgcn_sched_barrier(0);
}

// ---------------------------------------------------------------------------
// K1b: W -> bf16 (row-major)
// ---------------------------------------------------------------------------
__global__ __launch_bounds__(256) void k_cvtW(const float* __restrict__ W,
                                              u16* __restrict__ wbb) {
  int idx = (blockIdx.x * 256 + threadIdx.x) * 8;
  float4 a = *(const float4*)(W + idx);
  float4 b = *(const float4*)(W + idx + 4);
  float v[8] = {a.x, a.y, a.z, a.w, b.x, b.y, b.z, b.w};
  u32x4 pk;
#pragma unroll
  for (int j = 0; j < 4; ++j)
    pk[j] = (u32)f2bf(v[2 * j]) | ((u32)f2bf(v[2 * j + 1]) << 16);
  *(u32x4*)(wbb + idx) = pk;
}

// ---------------------------------------------------------------------------
// K2: fused per-(b,chunk) prep:
//   tanh(x-chunk) -> Kl LDS + kbs global (pre-swizzled bf16 rows)
//   G = K K^T (MFMA); T = (I+A)^{-1} (fwd subst, 4 lanes/col)
//   Outputs (bf16):
//     tbs[s][r] = lam^{63-s} * beta*T[s][r]          (B-phase, emits Ws)
//     tcs[s][r] = -lam^{63-s} * beta*T[s][r]*lam^{r+1}
//     p1g = Mt . (beta*T)          (C-phase)
//     p2g = Mt . (-beta*T*diag(lam^{r+1}))
//     kbt = K^T pre-swizzled [k][s]
// ---------------------------------------------------------------------------
__global__ __launch_bounds__(256) void k_prep3(const float* __restrict__ x,
                                               const float* __restrict__ eta_p,
                                               const float* __restrict__ ll_p,
                                               u16* __restrict__ kbs,
                                               u16* __restrict__ tbs,
                                               u16* __restrict__ tcs,
                                               u16* __restrict__ p1g,
                                               u16* __restrict__ p2g,
                                               u16* __restrict__ kbt) {
  __shared__ __align__(16) u16 Kl[CC * DD];   // 64 KB
  __shared__ float Gl[64 * 64];               // 16 KB
  __shared__ float Gs[64 * 64];               // 16 KB
  __shared__ float Tl[64 * 65];               // 16.25 KB
  __shared__ __align__(16) u16 MtL[64 * 64];  // 8 KB
  __shared__ __align__(16) u16 TbT[64 * 64];  // 8 KB
  __shared__ __align__(16) u16 TcT[64 * 64];  // 8 KB
  __shared__ float pw[72];
  int bc = blockIdx.x;
  int b = bc >> 5, c = bc & 31;
  int tid = threadIdx.x;
  int wid = tid >> 6, lane = tid & 63;
  int lo = lane & 15, hi = lane >> 4;
  float beta = *eta_p;
  float lam = 1.f / (1.f + expf(-*ll_p));
  if (tid <= 64) pw[tid] = powf(lam, (float)tid);
  for (int i = tid; i < 64 * 65; i += 256) Tl[i] = 0.f;
  // ---- tanh + pack: x chunk -> Kl (swizzled) + kbs global ----
  const float* xg = x + (size_t)(b * LL + c * CC) * DD;
  u16* kbs_c = kbs + (size_t)(b * LL + c * CC) * DD;
#pragma unroll
  for (int i = 0; i < 16; ++i) {
    int idx = tid + i * 256;
    int r = idx >> 6, k8 = (idx & 63) * 8;
    const float* xp = xg + (size_t)r * DD + k8;
    float4 a = *(const float4*)xp;
    float4 b4 = *(const float4*)(xp + 4);
    float v[8] = {a.x, a.y, a.z, a.w, b4.x, b4.y, b4.z, b4.w};
    u32x4 pk;
#pragma unroll
    for (int j = 0; j < 4; ++j)
      pk[j] = (u32)f2bf(tanhf(v[2 * j])) | ((u32)f2bf(tanhf(v[2 * j + 1])) << 16);
    int off = r * DD + (k8 ^ (sx6(r) << 3));
    *(u32x4*)(Kl + off) = pk;
    *(u32x4*)(kbs_c + off) = pk;
  }
  __syncthreads();
  // ---- G = K K^T via MFMA ----
  {
    f32x4 acc[4] = {{0.f,0.f,0.f,0.f},{0.f,0.f,0.f,0.f},{0.f,0.f,0.f,0.f},{0.f,0.f,0.f,0.f}};
    int t = 16 * wid + lo;
    int mT = sx6(t) << 3;
#pragma unroll
    for (int kq = 0; kq < 16; ++kq) {
      int col = hi * 8 + kq * 32;
      bf16x8 aF = ldf(Kl + t * DD + (col ^ mT));
#pragma unroll
      for (int sb = 0; sb < 4; ++sb) {
        int s = 16 * sb + lo;
        bf16x8 bF = ldf(Kl + s * DD + (col ^ (sx6(s) << 3)));
        acc[sb] = __builtin_amdgcn_mfma_f32_16x16x32_bf16(aF, bF, acc[sb], 0, 0, 0);
      }
    }
#pragma unroll
    for (int sb = 0; sb < 4; ++sb)
#pragma unroll
      for (int r = 0; r < 4; ++r)
        Gl[(16 * wid + 4 * hi + r) * 64 + 16 * sb + lo] = acc[sb][r];
  }
  __syncthreads();
#pragma unroll
  for (int i = 0; i < 16; ++i) {
    int idx = tid + i * 256;
    int tq = idx >> 6, sq = idx & 63;
    Gs[idx] = (sq < tq) ? beta * pw[tq - sq] * Gl[idx] : 0.f;
  }
  __syncthreads();
  // ---- forward substitution ----
  {
    int q = hi;
    int j = 16 * wid + lo;
    for (int t = 0; t < 64; ++t) {
      float ps = 0.f;
#pragma unroll
      for (int i = 0; i < 16; ++i) {
        int s = 16 * q + i;
        ps = fmaf(Gs[t * 64 + s], Tl[s * 65 + j], ps);
      }
      ps += __shfl_xor(ps, 16, 64);
      ps += __shfl_xor(ps, 32, 64);
      if (q == 0) Tl[t * 65 + j] = ((t == j) ? 1.f : 0.f) - ps;
    }
  }
  __syncthreads();
  // ---- tbs/tcs outputs + bf16 LDS tiles for P-GEMMs ----
  u16* tbso = tbs + (size_t)bc * 4096;
  u16* tcso = tcs + (size_t)bc * 4096;
#pragma unroll
  for (int i = 0; i < 16; ++i) {
    int idx = tid + i * 256;
    int s = idx >> 6, r = idx & 63;
    float tv = Tl[s * 65 + r];          // T[s][r]
    float sc = pw[63 - s] * beta;
    tbso[idx] = f2bf(sc * tv);
    tcso[idx] = f2bf(-sc * pw[r + 1] * tv);
    int swz = r ^ (sx6(s) << 3);
    float mtv = (r < s) ? pw[s - r] * Gl[s * 64 + r]
                        : ((r == s) ? Gl[s * 64 + r] : 0.f);
    MtL[s * 64 + swz] = f2bf(mtv);
    float tvT = Tl[r * 65 + s];         // T[r][s]  (row s of T^T)
    TbT[s * 64 + swz] = f2bf(beta * tvT);
    TcT[s * 64 + swz] = f2bf(-beta * pw[s + 1] * tvT);
  }
  __syncthreads();
  // ---- P1 = Mt.Tb, P2 = Mt.Tc via MFMA (each wave: 16 s-rows) ----
  {
    f32x4 p1a[4], p2a[4];
#pragma unroll
    for (int rt = 0; rt < 4; ++rt) {
      p1a[rt] = (f32x4){0.f, 0.f, 0.f, 0.f};
      p2a[rt] = (f32x4){0.f, 0.f, 0.f, 0.f};
    }
    int srow = 16 * wid + lo;
    int aswz = sx6(srow) << 3;
#pragma unroll
    for (int km = 0; km < 2; ++km) {
      int mo = hi * 8 + km * 32;
      bf16x8 aF = ldf(MtL + srow * 64 + (mo ^ aswz));
#pragma unroll
      for (int rt = 0; rt < 4; ++rt) {
        int rrow = 16 * rt + lo;
        int bswz = sx6(rrow) << 3;
        p1a[rt] = __builtin_amdgcn_mfma_f32_16x16x32_bf16(
            aF, ldf(TbT + rrow * 64 + (mo ^ bswz)), p1a[rt], 0, 0, 0);
        p2a[rt] = __builtin_amdgcn_mfma_f32_16x16x32_bf16(
            aF, ldf(TcT + rrow * 64 + (mo ^ bswz)), p2a[rt], 0, 0, 0);
      }
    }
    u16* p1o = p1g + (size_t)bc * 4096;
    u16* p2o = p2g + (size_t)bc * 4096;
#pragma unroll
    for (int rt = 0; rt < 4; ++rt)
#pragma unroll
      for (int rg = 0; rg < 4; ++rg) {
        int s = 16 * wid + 4 * hi + rg;
        int r = 16 * rt + lo;
        p1o[s * 64 + r] = f2bf(p1a[rt][rg]);
        p2o[s * 64 + r] = f2bf(p2a[rt][rg]);
      }
  }
  // ---- kbt = K^T, swizzled ----
  u16* ktb = kbt + (size_t)bc * CC * DD;
#pragma unroll
  for (int rr = 0; rr < 2; ++rr) {
    int k = rr * 256 + tid;
    int kbase = k & ~7, klo = k & 7;
    int mk = sx6(k) << 3;
#pragma unroll
    for (int g = 0; g < 8; ++g) {
      u32 w4[4];
#pragma unroll
      for (int p = 0; p < 4; ++p) {
        int s0 = g * 8 + 2 * p;
        u16 e0 = Kl[s0 * DD + (kbase ^ (sx6(s0) << 3)) + klo];
        u16 e1 = Kl[(s0 + 1) * DD + (kbase ^ (sx6(s0 + 1) << 3)) + klo];
        w4[p] = (u32)e0 | ((u32)e1 << 16);
      }
      *(u32x4*)(ktb + (size_t)k * 64 + ((8 * g) ^ mk)) = (u32x4){w4[0], w4[1], w4[2], w4[3]};
    }
  }
}

// ---------------------------------------------------------------------------
// K3: MFMA chunked scan, 512 thr (8 waves), k-split 2, B||C decoupled, V-hoist.
//   A(U) -> bar -> stage-write+reduce -> bar ->
//   { B(kh0): Ws = tbs.V + tcs.U ; C(kh1): O = csc.U + p1.V + p2.U + y ;
//     all: V[c+1] } -> bar -> D + prefetch -> bar
// ---------------------------------------------------------------------------
__global__ __launch_bounds__(512, 2) void k_scan8(const u16* __restrict__ kbs,
                                                  const u16* __restrict__ kbt,
                                                  const u16* __restrict__ wbb,
                                                  const u16* __restrict__ tbs,
                                                  const u16* __restrict__ tcs,
                                                  const u16* __restrict__ p1g,
                                                  const u16* __restrict__ p2g,
                                                  const float* __restrict__ ll_p,
                                                  float* __restrict__ y) {
  __shared__ __align__(16) u16 Kl[CC * DD];     // 64 KB
  __shared__ __align__(16) u16 Sb[16 * DD];     // 16 KB bf16 state copy
  __shared__ float Vp[2 * 16 * 68];             // 8.5 KB fp32 V partials
  __shared__ float Up[2 * 16 * 68];             // 8.5 KB fp32 U partials
  __shared__ __align__(16) u16 Vt[16 * 64];
  __shared__ __align__(16) u16 Ut[16 * 64];
  __shared__ __align__(16) u16 Ws[16 * 64];

  int b = blockIdx.x >> 6;
  int vb = blockIdx.x & 63;
  int v0 = vb * VB;
  int tid = threadIdx.x;
  int wid = tid >> 6, lane = tid & 63;
  int wq = wid & 3, kh = wid >> 2;
  int lo = lane & 15, hi = lane >> 4;
  int sidx = 16 * wq + lo;
  int mK = sx6(sidx) << 3;
  int mLo = sx6(lo) << 3;
  int kOff = kh * 256;

  float lam = 1.f / (1.f + expf(-*ll_p));
  float lam64 = powf(lam, 64.f);
  float csc = powf(lam, (float)(sidx + 1));

  {
    u32x4 z = {0u, 0u, 0u, 0u};
    *((u32x4*)Sb + tid) = z;
    *((u32x4*)Sb + 512 + tid) = z;
    if (tid < 384) {
      u16* base = (tid >> 7) == 0 ? Vt : (tid >> 7) == 1 ? Ut : Ws;
      *((u32x4*)base + (tid & 127)) = z;
    }
  }
  const u16* kb_b = kbs + (size_t)b * LL * DD;
  float* yb = y + (size_t)b * LL * DD;

  // W A-fragments (chunk-invariant, k-half)
  u32x4 wf[8];
#pragma unroll
  for (int kq = 0; kq < 8; ++kq)
    wf[kq] = *(const u32x4*)(wbb + (size_t)((v0 + lo) & 511) * DD + kOff + hi * 8 + kq * 32);

  // prologue: stage chunk 0, frames for chunk 0
  u32x4 sreg[8];
#pragma unroll
  for (int i = 0; i < 8; ++i)
    sreg[i] = *(const u32x4*)(kb_b + (size_t)(i * 512 + tid) * 8);
  u32x4 kt0[4], kt1[4], fA0, fA1, fB0, fB1;
  {
    const u16* ktc = kbt + (size_t)(b * NC + 0) * CC * DD;
#pragma unroll
    for (int t = 0; t < 4; ++t) {
      int k = 16 * (4 * wid + t) + lo;
      const u16* rowp = ktc + (size_t)k * 64;
      int m = sx6(k) << 3;
      kt0[t] = *(const u32x4*)(rowp + ((8 * hi) ^ m));
      kt1[t] = *(const u32x4*)(rowp + ((8 * hi + 32) ^ m));
    }
    size_t tbase = ((size_t)(b * NC + 0) * 64 + sidx) * 64 + hi * 8;
    const u16* mA = (kh == 0) ? tbs : p1g;
    const u16* mB = (kh == 0) ? tcs : p2g;
    fA0 = *(const u32x4*)(mA + tbase);
    fA1 = *(const u32x4*)(mA + tbase + 32);
    fB0 = *(const u32x4*)(mB + tbase);
    fB1 = *(const u32x4*)(mB + tbase + 32);
  }
#pragma unroll
  for (int i = 0; i < 8; ++i)
    *(u32x4*)(Kl + (size_t)(i * 512 + tid) * 8) = sreg[i];

  f32x4 Sa[4];
#pragma unroll
  for (int t = 0; t < 4; ++t) Sa[t] = (f32x4){0.f, 0.f, 0.f, 0.f};
  barrier_all();

  // prologue: V[0] partials
  {
    f32x4 Va0 = {0.f,0.f,0.f,0.f}, Va1 = {0.f,0.f,0.f,0.f};
#pragma unroll
    for (int kq = 0; kq < 8; ++kq) {
      int col = kOff + hi * 8 + kq * 32;
      bf16x8 kB = ldf(Kl + sidx * DD + (col ^ mK));
      if (kq & 1) Va1 = __builtin_amdgcn_mfma_f32_16x16x32_bf16(bcv(wf[kq]), kB, Va1, 0, 0, 0);
      else        Va0 = __builtin_amdgcn_mfma_f32_16x16x32_bf16(bcv(wf[kq]), kB, Va0, 0, 0, 0);
    }
    f32x4 Va = Va0 + Va1;
#pragma unroll
    for (int r = 0; r < 4; ++r)
      Vp[(kh * 16 + 4 * hi + r) * 68 + sidx] = Va[r];
  }

  for (int c = 0; c < NC; ++c) {
    // issue stage loads for c+1
    if (c + 1 < NC) {
      const u16* src = kb_b + (size_t)(c + 1) * CC * DD;
#pragma unroll
      for (int i = 0; i < 8; ++i)
        sreg[i] = *(const u32x4*)(src + (size_t)(i * 512 + tid) * 8);
    }
    // ---- phase A: U partials ----
    {
      f32x4 Ua0 = {0.f,0.f,0.f,0.f}, Ua1 = {0.f,0.f,0.f,0.f};
#pragma unroll
      for (int kq = 0; kq < 8; ++kq) {
        int col = kOff + hi * 8 + kq * 32;
        bf16x8 kB = ldf(Kl + sidx * DD + (col ^ mK));
        bf16x8 sA = ldf(Sb + lo * DD + (col ^ mLo));
        if (kq & 1) Ua1 = __builtin_amdgcn_mfma_f32_16x16x32_bf16(sA, kB, Ua1, 0, 0, 0);
        else        Ua0 = __builtin_amdgcn_mfma_f32_16x16x32_bf16(sA, kB, Ua0, 0, 0, 0);
      }
      f32x4 Ua = Ua0 + Ua1;
#pragma unroll
      for (int r = 0; r < 4; ++r)
        Up[(kh * 16 + 4 * hi + r) * 68 + sidx] = Ua[r];
    }
    barrier_lgkm();
    // stage-write c+1 into Kl
    if (c + 1 < NC) {
#pragma unroll
      for (int i = 0; i < 8; ++i)
        *(u32x4*)(Kl + (size_t)(i * 512 + tid) * 8) = sreg[i];
    }
    // ---- reduce (all waves) + tiles (kh0) ----
    float UaF[4], VaF[4];
#pragma unroll
    for (int r = 0; r < 4; ++r) {
      int v = 4 * hi + r;
      UaF[r] = Up[v * 68 + sidx] + Up[(16 + v) * 68 + sidx];
      VaF[r] = Vp[v * 68 + sidx] + Vp[(16 + v) * 68 + sidx];
    }
    if (kh == 0 && hi < 2) {
#pragma unroll
      for (int r = 0; r < 4; ++r) {
        int v = 4 * hi + r;
        int idx = v * 64 + (sidx ^ (sx6(v) << 3));
        Ut[idx] = f2bf(UaF[r]);
        Vt[idx] = f2bf(VaF[r]);
      }
    }
    barrier_lgkm();
    // ---- B (kh0) || C+y (kh1) || V[c+1] (all) ----
    {
      bf16x8 vf0 = ldf(Vt + lo * 64 + ((hi * 8) ^ mLo));
      bf16x8 vf1 = ldf(Vt + lo * 64 + ((hi * 8 + 32) ^ mLo));
      bf16x8 uf0 = ldf(Ut + lo * 64 + ((hi * 8) ^ mLo));
      bf16x8 uf1 = ldf(Ut + lo * 64 + ((hi * 8 + 32) ^ mLo));
      if (kh == 0) {
        f32x4 Wa0 = {0.f,0.f,0.f,0.f}, Wa1 = {0.f,0.f,0.f,0.f};
        Wa0 = __builtin_amdgcn_mfma_f32_16x16x32_bf16(vf0, bcv(fA0), Wa0, 0, 0, 0);
        Wa1 = __builtin_amdgcn_mfma_f32_16x16x32_bf16(vf1, bcv(fA1), Wa1, 0, 0, 0);
        Wa0 = __builtin_amdgcn_mfma_f32_16x16x32_bf16(uf0, bcv(fB0), Wa0, 0, 0, 0);
        Wa1 = __builtin_amdgcn_mfma_f32_16x16x32_bf16(uf1, bcv(fB1), Wa1, 0, 0, 0);
        f32x4 Wa = Wa0 + Wa1;
        if (hi < 2) {
#pragma unroll
          for (int r = 0; r < 4; ++r) {
            int v = 4 * hi + r;
            Ws[v * 64 + (sidx ^ (sx6(v) << 3))] = f2bf(Wa[r]);
          }
        }
      } else {
        f32x4 Oa, Ob = {0.f,0.f,0.f,0.f};
#pragma unroll
        for (int r = 0; r < 4; ++r) Oa[r] = csc * UaF[r];
        Oa = __builtin_amdgcn_mfma_f32_16x16x32_bf16(vf0, bcv(fA0), Oa, 0, 0, 0);
        Ob = __builtin_amdgcn_mfma_f32_16x16x32_bf16(vf1, bcv(fA1), Ob, 0, 0, 0);
        Oa = __builtin_amdgcn_mfma_f32_16x16x32_bf16(uf0, bcv(fB0), Oa, 0, 0, 0);
        Ob = __builtin_amdgcn_mfma_f32_16x16x32_bf16(uf1, bcv(fB1), Ob, 0, 0, 0);
        if (hi < 2) {
          float4 yo = make_float4(VaF[0] + Oa[0] + Ob[0], VaF[1] + Oa[1] + Ob[1],
                                  VaF[2] + Oa[2] + Ob[2], VaF[3] + Oa[3] + Ob[3]);
          *(float4*)(yb + (size_t)(c * CC + sidx) * DD + v0 + 4 * hi) = yo;
        }
      }
    }
    // V[c+1] (Kl = K[c+1] after bar2)
    if (c + 1 < NC) {
      f32x4 Va0 = {0.f,0.f,0.f,0.f}, Va1 = {0.f,0.f,0.f,0.f};
#pragma unroll
      for (int kq = 0; kq < 8; ++kq) {
        int col = kOff + hi * 8 + kq * 32;
        bf16x8 kB = ldf(Kl + sidx * DD + (col ^ mK));
        if (kq & 1) Va1 = __builtin_amdgcn_mfma_f32_16x16x32_bf16(bcv(wf[kq]), kB, Va1, 0, 0, 0);
        else        Va0 = __builtin_amdgcn_mfma_f32_16x16x32_bf16(bcv(wf[kq]), kB, Va0, 0, 0, 0);
      }
      f32x4 Va = Va0 + Va1;
#pragma unroll
      for (int r = 0; r < 4; ++r)
        Vp[(kh * 16 + 4 * hi + r) * 68 + sidx] = Va[r];
    }
    barrier_lgkm();
    // ---- phase D ----
    {
      bf16x8 ws0 = ldf(Ws + lo * 64 + ((hi * 8) ^ mLo));
      bf16x8 ws1 = ldf(Ws + lo * 64 + ((hi * 8 + 32) ^ mLo));
#pragma unroll
      for (int t = 0; t < 4; ++t) {
        f32x4 acc = Sa[t] * lam64;
        acc = __builtin_amdgcn_mfma_f32_16x16x32_bf16(ws0, bcv(kt0[t]), acc, 0, 0, 0);
        acc = __builtin_amdgcn_mfma_f32_16x16x32_bf16(ws1, bcv(kt1[t]), acc, 0, 0, 0);
        Sa[t] = acc;
      }
      if (hi < 2) {
#pragma unroll
        for (int t = 0; t < 4; ++t) {
          int kc = 16 * (4 * wid + t) + lo;
#pragma unroll
          for (int r = 0; r < 4; ++r) {
            int v = 4 * hi + r;
            Sb[v * DD + (kc ^ (sx6(v) << 3))] = f2bf(Sa[t][r]);
          }
        }
      }
    }
    // ---- prefetch frames for c+1 ----
    if (c + 1 < NC) {
      const u16* ktc = kbt + (size_t)(b * NC + c + 1) * CC * DD;
#pragma unroll
      for (int t = 0; t < 4; ++t) {
        int k = 16 * (4 * wid + t) + lo;
        const u16* rowp = ktc + (size_t)k * 64;
        int m = sx6(k) << 3;
        kt0[t] = *(const u32x4*)(rowp + ((8 * hi) ^ m));
        kt1[t] = *(const u32x4*)(rowp + ((8 * hi + 32) ^ m));
      }
      size_t tbase = ((size_t)(b * NC + c + 1) * 64 + sidx) * 64 + hi * 8;
      const u16* mA = (kh == 0) ? tbs : p1g;
      const u16* mB = (kh == 0) ? tcs : p2g;
      fA0 = *(const u32x4*)(mA + tbase);
      fA1 = *(const u32x4*)(mA + tbase + 32);
      fB0 = *(const u32x4*)(mB + tbase);
      fB1 = *(const u32x4*)(mB + tbase + 32);
    }
    barrier_lgkm();
  }
}

// ---------------------------------------------------------------------------
// K4: LayerNorm in-place on d_out.
// ---------------------------------------------------------------------------
__global__ __launch_bounds__(256) void k_ln(float* __restrict__ y,
                                            const float* __restrict__ gamma,
                                            const float* __restrict__ lbeta) {
  int row = blockIdx.x * 4 + (threadIdx.x >> 6);
  int lane = threadIdx.x & 63;
  float* yr = y + (size_t)row * DD + lane * 8;
  float4 a = *(const float4*)yr;
  float4 b = *(const float4*)(yr + 4);
  float v[8] = {a.x, a.y, a.z, a.w, b.x, b.y, b.z, b.w};
  float s = 0.f, ss = 0.f;
#pragma unroll
  for (int j = 0; j < 8; ++j) {
    s += v[j];
    ss = fmaf(v[j], v[j], ss);
  }
#pragma unroll
  for (int m = 1; m < 64; m <<= 1) {
    s += __shfl_xor(s, m, 64);
    ss += __shfl_xor(ss, m, 64);
  }
  float mu = s * (1.f / DD);
  float var = ss * (1.f / DD) - mu * mu;
  float inv = rsqrtf(var + EPSF);
  const float* gp = gamma + lane * 8;
  const float* bp = lbeta + lane * 8;
  float4 g0 = *(const float4*)gp;
  float4 g1 = *(const float4*)(gp + 4);
  float4 b0 = *(const float4*)bp;
  float4 b1 = *(const float4*)(bp + 4);
  float g[8] = {g0.x, g0.y, g0.z, g0.w, g1.x, g1.y, g1.z, g1.w};
  float bb[8] = {b0.x, b0.y, b0.z, b0.w, b1.x, b1.y, b1.z, b1.w};
#pragma unroll
  for (int j = 0; j < 8; ++j) v[j] = (v[j] - mu) * inv * g[j] + bb[j];
  *(float4*)yr = make_float4(v[0], v[1], v[2], v[3]);
  *(float4*)(yr + 4) = make_float4(v[4], v[5], v[6], v[7]);
}

// ---------------------------------------------------------------------------
extern "C" void kernel_launch(void* const* d_in, const int* in_sizes, int n_in,
                              void* d_out, int out_size, void* d_ws, size_t ws_size,
                              hipStream_t stream) {
  const float* x     = (const float*)d_in[0];
  const float* W     = (const float*)d_in[1];
  const float* eta   = (const float*)d_in[2];
  const float* ll    = (const float*)d_in[3];
  const float* gamma = (const float*)d_in[4];
  const float* lbeta = (const float*)d_in[5];
  float* out = (float*)d_out;

  // ws (u16): kbs 8MB | kbt 8MB | wbb 0.5MB | tbs/tcs/p1/p2 1MB each (~20.5MB)
  u16* kbs = (u16*)d_ws;
  u16* kbt = kbs + (size_t)BB * LL * DD;
  u16* wbb = kbt + (size_t)BB * LL * DD;
  u16* tbs = wbb + (size_t)DD * DD;
  u16* tcs = tbs + (size_t)BB * NC * 64 * 64;
  u16* p1g = tcs + (size_t)BB * NC * 64 * 64;
  u16* p2g = p1g + (size_t)BB * NC * 64 * 64;

  k_cvtW<<<128, 256, 0, stream>>>(W, wbb);
  k_prep3<<<BB * NC, 256, 0, stream>>>(x, eta, ll, kbs, tbs, tcs, p1g, p2g, kbt);
  k_scan8<<<256, 512, 0, stream>>>(kbs, kbt, wbb, tbs, tcs, p1g, p2g, ll, out);
  k_ln<<<2048, 256, 0, stream>>>(out, gamma, lbeta);
}

// Round 10
// 149.748 us; speedup vs baseline: 2.7344x; 1.1570x over previous
//
#include <hip/hip_runtime.h>
#include <math.h>

#define BB 4
#define LL 2048
#define DD 512
#define CC 64      // chunk length
#define NC 32      // number of chunks
#define VB 8       // v-columns owned per workgroup
#define EPSF 1e-5f

typedef unsigned int u32;
typedef unsigned short u16;
typedef __attribute__((ext_vector_type(4))) u32 u32x4;
typedef __attribute__((ext_vector_type(4))) float f32x4;
typedef __attribute__((ext_vector_type(8))) __bf16 bf16x8;

__device__ __forceinline__ u16 f2bf(float f) {           // native RNE cvt
  return __builtin_bit_cast(u16, (__bf16)f);
}
__device__ __forceinline__ int sx6(int s) { return (s ^ (s >> 3)) & 7; }
__device__ __forceinline__ bf16x8 ldf(const u16* p) {
  return __builtin_bit_cast(bf16x8, *(const u32x4*)p);
}
__device__ __forceinline__ bf16x8 bcv(u32x4 v) { return __builtin_bit_cast(bf16x8, v); }

__device__ __forceinline__ void gld16(u16* lds, const u16* g) {
  __builtin_amdgcn_global_load_lds(
      (const __attribute__((address_space(1))) u32*)g,
      (__attribute__((address_space(3))) u32*)lds, 16, 0, 0);
}
// barrier that drains only LDS (keeps global loads in flight)
__device__ __forceinline__ void barrier_lgkm() {
  asm volatile("s_waitcnt lgkmcnt(0)" ::: "memory");
  __builtin_amdgcn_sched_barrier(0);
  __builtin_amdgcn_s_barrier();
  __builtin_amdgcn_sched_barrier(0);
}
__device__ __forceinline__ void barrier_all() {
  asm volatile("s_waitcnt vmcnt(0) lgkmcnt(0)" ::: "memory");
  __builtin_amdgcn_sched_barrier(0);
  __builtin_amdgcn_s_barrier();
  __builtin_amdgcn_sched_barrier(0);
}

// ---------------------------------------------------------------------------
// K1b: W -> bf16 (row-major)
// ---------------------------------------------------------------------------
__global__ __launch_bounds__(256) void k_cvtW(const float* __restrict__ W,
                                              u16* __restrict__ wbb) {
  int idx = (blockIdx.x * 256 + threadIdx.x) * 8;
  float4 a = *(const float4*)(W + idx);
  float4 b = *(const float4*)(W + idx + 4);
  float v[8] = {a.x, a.y, a.z, a.w, b.x, b.y, b.z, b.w};
  u32x4 pk;
#pragma unroll
  for (int j = 0; j < 4; ++j)
    pk[j] = (u32)f2bf(v[2 * j]) | ((u32)f2bf(v[2 * j + 1]) << 16);
  *(u32x4*)(wbb + idx) = pk;
}

// ---------------------------------------------------------------------------
// K2: fused per-(b,chunk) prep (same as R9):
//   tanh(x-chunk) -> Kl LDS + kbs global (pre-swizzled bf16 rows)
//   G = K K^T (MFMA); T = (I+A)^{-1} (fwd subst, 4 lanes/col)
//   tbs[s][r] = lam^{63-s}*beta*T ; tcs = -lam^{63-s}*beta*T*lam^{r+1}
//   p1g = Mt.(beta*T) ; p2g = Mt.(-beta*T*diag(lam^{r+1})) ; kbt = K^T swz
// ---------------------------------------------------------------------------
__global__ __launch_bounds__(256) void k_prep3(const float* __restrict__ x,
                                               const float* __restrict__ eta_p,
                                               const float* __restrict__ ll_p,
                                               u16* __restrict__ kbs,
                                               u16* __restrict__ tbs,
                                               u16* __restrict__ tcs,
                                               u16* __restrict__ p1g,
                                               u16* __restrict__ p2g,
                                               u16* __restrict__ kbt) {
  __shared__ __align__(16) u16 Kl[CC * DD];   // 64 KB
  __shared__ float Gl[64 * 64];
  __shared__ float Gs[64 * 64];
  __shared__ float Tl[64 * 65];
  __shared__ __align__(16) u16 MtL[64 * 64];
  __shared__ __align__(16) u16 TbT[64 * 64];
  __shared__ __align__(16) u16 TcT[64 * 64];
  __shared__ float pw[72];
  int bc = blockIdx.x;
  int b = bc >> 5, c = bc & 31;
  int tid = threadIdx.x;
  int wid = tid >> 6, lane = tid & 63;
  int lo = lane & 15, hi = lane >> 4;
  float beta = *eta_p;
  float lam = 1.f / (1.f + expf(-*ll_p));
  if (tid <= 64) pw[tid] = powf(lam, (float)tid);
  for (int i = tid; i < 64 * 65; i += 256) Tl[i] = 0.f;
  // ---- tanh + pack ----
  const float* xg = x + (size_t)(b * LL + c * CC) * DD;
  u16* kbs_c = kbs + (size_t)(b * LL + c * CC) * DD;
#pragma unroll
  for (int i = 0; i < 16; ++i) {
    int idx = tid + i * 256;
    int r = idx >> 6, k8 = (idx & 63) * 8;
    const float* xp = xg + (size_t)r * DD + k8;
    float4 a = *(const float4*)xp;
    float4 b4 = *(const float4*)(xp + 4);
    float v[8] = {a.x, a.y, a.z, a.w, b4.x, b4.y, b4.z, b4.w};
    u32x4 pk;
#pragma unroll
    for (int j = 0; j < 4; ++j)
      pk[j] = (u32)f2bf(tanhf(v[2 * j])) | ((u32)f2bf(tanhf(v[2 * j + 1])) << 16);
    int off = r * DD + (k8 ^ (sx6(r) << 3));
    *(u32x4*)(Kl + off) = pk;
    *(u32x4*)(kbs_c + off) = pk;
  }
  __syncthreads();
  // ---- G = K K^T ----
  {
    f32x4 acc[4] = {{0.f,0.f,0.f,0.f},{0.f,0.f,0.f,0.f},{0.f,0.f,0.f,0.f},{0.f,0.f,0.f,0.f}};
    int t = 16 * wid + lo;
    int mT = sx6(t) << 3;
#pragma unroll
    for (int kq = 0; kq < 16; ++kq) {
      int col = hi * 8 + kq * 32;
      bf16x8 aF = ldf(Kl + t * DD + (col ^ mT));
#pragma unroll
      for (int sb = 0; sb < 4; ++sb) {
        int s = 16 * sb + lo;
        bf16x8 bF = ldf(Kl + s * DD + (col ^ (sx6(s) << 3)));
        acc[sb] = __builtin_amdgcn_mfma_f32_16x16x32_bf16(aF, bF, acc[sb], 0, 0, 0);
      }
    }
#pragma unroll
    for (int sb = 0; sb < 4; ++sb)
#pragma unroll
      for (int r = 0; r < 4; ++r)
        Gl[(16 * wid + 4 * hi + r) * 64 + 16 * sb + lo] = acc[sb][r];
  }
  __syncthreads();
#pragma unroll
  for (int i = 0; i < 16; ++i) {
    int idx = tid + i * 256;
    int tq = idx >> 6, sq = idx & 63;
    Gs[idx] = (sq < tq) ? beta * pw[tq - sq] * Gl[idx] : 0.f;
  }
  __syncthreads();
  // ---- forward substitution ----
  {
    int q = hi;
    int j = 16 * wid + lo;
    for (int t = 0; t < 64; ++t) {
      float ps = 0.f;
#pragma unroll
      for (int i = 0; i < 16; ++i) {
        int s = 16 * q + i;
        ps = fmaf(Gs[t * 64 + s], Tl[s * 65 + j], ps);
      }
      ps += __shfl_xor(ps, 16, 64);
      ps += __shfl_xor(ps, 32, 64);
      if (q == 0) Tl[t * 65 + j] = ((t == j) ? 1.f : 0.f) - ps;
    }
  }
  __syncthreads();
  // ---- tbs/tcs + LDS tiles for P GEMMs ----
  u16* tbso = tbs + (size_t)bc * 4096;
  u16* tcso = tcs + (size_t)bc * 4096;
#pragma unroll
  for (int i = 0; i < 16; ++i) {
    int idx = tid + i * 256;
    int s = idx >> 6, r = idx & 63;
    float tv = Tl[s * 65 + r];
    float sc = pw[63 - s] * beta;
    tbso[idx] = f2bf(sc * tv);
    tcso[idx] = f2bf(-sc * pw[r + 1] * tv);
    int swz = r ^ (sx6(s) << 3);
    float mtv = (r < s) ? pw[s - r] * Gl[s * 64 + r]
                        : ((r == s) ? Gl[s * 64 + r] : 0.f);
    MtL[s * 64 + swz] = f2bf(mtv);
    float tvT = Tl[r * 65 + s];
    TbT[s * 64 + swz] = f2bf(beta * tvT);
    TcT[s * 64 + swz] = f2bf(-beta * pw[s + 1] * tvT);
  }
  __syncthreads();
  // ---- P1 = Mt.Tb, P2 = Mt.Tc ----
  {
    f32x4 p1a[4], p2a[4];
#pragma unroll
    for (int rt = 0; rt < 4; ++rt) {
      p1a[rt] = (f32x4){0.f, 0.f, 0.f, 0.f};
      p2a[rt] = (f32x4){0.f, 0.f, 0.f, 0.f};
    }
    int srow = 16 * wid + lo;
    int aswz = sx6(srow) << 3;
#pragma unroll
    for (int km = 0; km < 2; ++km) {
      int mo = hi * 8 + km * 32;
      bf16x8 aF = ldf(MtL + srow * 64 + (mo ^ aswz));
#pragma unroll
      for (int rt = 0; rt < 4; ++rt) {
        int rrow = 16 * rt + lo;
        int bswz = sx6(rrow) << 3;
        p1a[rt] = __builtin_amdgcn_mfma_f32_16x16x32_bf16(
            aF, ldf(TbT + rrow * 64 + (mo ^ bswz)), p1a[rt], 0, 0, 0);
        p2a[rt] = __builtin_amdgcn_mfma_f32_16x16x32_bf16(
            aF, ldf(TcT + rrow * 64 + (mo ^ bswz)), p2a[rt], 0, 0, 0);
      }
    }
    u16* p1o = p1g + (size_t)bc * 4096;
    u16* p2o = p2g + (size_t)bc * 4096;
#pragma unroll
    for (int rt = 0; rt < 4; ++rt)
#pragma unroll
      for (int rg = 0; rg < 4; ++rg) {
        int s = 16 * wid + 4 * hi + rg;
        int r = 16 * rt + lo;
        p1o[s * 64 + r] = f2bf(p1a[rt][rg]);
        p2o[s * 64 + r] = f2bf(p2a[rt][rg]);
      }
  }
  // ---- kbt = K^T, swizzled ----
  u16* ktb = kbt + (size_t)bc * CC * DD;
#pragma unroll
  for (int rr = 0; rr < 2; ++rr) {
    int k = rr * 256 + tid;
    int kbase = k & ~7, klo = k & 7;
    int mk = sx6(k) << 3;
#pragma unroll
    for (int g = 0; g < 8; ++g) {
      u32 w4[4];
#pragma unroll
      for (int p = 0; p < 4; ++p) {
        int s0 = g * 8 + 2 * p;
        u16 e0 = Kl[s0 * DD + (kbase ^ (sx6(s0) << 3)) + klo];
        u16 e1 = Kl[(s0 + 1) * DD + (kbase ^ (sx6(s0 + 1) << 3)) + klo];
        w4[p] = (u32)e0 | ((u32)e1 << 16);
      }
      *(u32x4*)(ktb + (size_t)k * 64 + ((8 * g) ^ mk)) = (u32x4){w4[0], w4[1], w4[2], w4[3]};
    }
  }
}

// ---------------------------------------------------------------------------
// K3: MFMA chunked scan v9. 512 thr (8 waves = wq x kh), 2 waves/SIMD.
//   - K B-frags in REGISTERS (direct per-lane global loads; no Kl LDS).
//   - U+V packed in one MFMA M-dim: Sb rows0-7 = S^T bf16, rows8-15 = W rows.
//   - Schedule: UV(8 mfma) -> bar -> reduce (+kB prefetch) -> bar ->
//               B(kh0,4) || C+y(kh1,4) -> bar -> D(8) (+kt/frames prefetch) -> bar
//   - V reaches y via __shfl_xor(.,32) (fp32 exact).
// ---------------------------------------------------------------------------
__global__ __launch_bounds__(512, 2) void k_scan9(const u16* __restrict__ kbs,
                                                  const u16* __restrict__ kbt,
                                                  const u16* __restrict__ wbb,
                                                  const u16* __restrict__ tbs,
                                                  const u16* __restrict__ tcs,
                                                  const u16* __restrict__ p1g,
                                                  const u16* __restrict__ p2g,
                                                  const float* __restrict__ ll_p,
                                                  float* __restrict__ y) {
  __shared__ __align__(16) u16 Sb[16 * DD];       // 16 KB: rows0-7 S, rows8-15 W
  __shared__ __align__(16) float Up[2][64][20];   // 10.25 KB fp32 partials [kh][s][m]
  __shared__ __align__(16) u16 Vt[16 * 64];
  __shared__ __align__(16) u16 Ut[16 * 64];
  __shared__ __align__(16) u16 Ws[16 * 64];

  int b = blockIdx.x >> 6;
  int vb = blockIdx.x & 63;
  int v0 = vb * VB;
  int tid = threadIdx.x;
  int wid = tid >> 6, lane = tid & 63;
  int wq = wid & 3, kh = wid >> 2;
  int lo = lane & 15, hi = lane >> 4;
  int sidx = 16 * wq + lo;
  int mS = sx6(sidx) << 3;     // swizzle for kbs row sidx
  int mLo = sx6(lo) << 3;      // swizzle for LDS row lo
  int kOff = kh * 256;

  float lam = 1.f / (1.f + expf(-*ll_p));
  float lam64 = powf(lam, 64.f);
  float csc = powf(lam, (float)(sidx + 1));

  // ---- init LDS: S rows zero, W rows, tiles zero ----
  {
    u32x4 z = {0u, 0u, 0u, 0u};
    *((u32x4*)Sb + tid) = z;               // rows 0-7 (8 KB)
    if (tid < 384) {
      u16* base = (tid >> 7) == 0 ? Vt : (tid >> 7) == 1 ? Ut : Ws;
      *((u32x4*)base + (tid & 127)) = z;
    }
    int r8 = wid;  // 0..7 -> W row v0+r8 into Sb row 8+r8
    u32x4 wrow = *(const u32x4*)(wbb + (size_t)(v0 + r8) * DD + lane * 8);
    *(u32x4*)(Sb + (size_t)(8 + r8) * DD + ((lane * 8) ^ (sx6(8 + r8) << 3))) = wrow;
  }
  const u16* kb_b = kbs + (size_t)b * LL * DD;
  float* yb = y + (size_t)b * LL * DD;

  // ---- prologue global loads: kB chunk0, kt chunk0, frames chunk0 ----
  u32x4 kB[8];
#pragma unroll
  for (int kq = 0; kq < 8; ++kq)
    kB[kq] = *(const u32x4*)(kb_b + (size_t)sidx * DD +
                             ((kOff + hi * 8 + kq * 32) ^ mS));
  u32x4 kt0[4], kt1[4], fA0, fA1, fB0, fB1;
  {
    const u16* ktc = kbt + (size_t)(b * NC + 0) * CC * DD;
#pragma unroll
    for (int t = 0; t < 4; ++t) {
      int k = 16 * (4 * wid + t) + lo;
      const u16* rowp = ktc + (size_t)k * 64;
      int m = sx6(k) << 3;
      kt0[t] = *(const u32x4*)(rowp + ((8 * hi) ^ m));
      kt1[t] = *(const u32x4*)(rowp + ((8 * hi + 32) ^ m));
    }
    size_t tbase = ((size_t)(b * NC + 0) * 64 + sidx) * 64 + hi * 8;
    const u16* mA = (kh == 0) ? tbs : p1g;
    const u16* mB = (kh == 0) ? tcs : p2g;
    fA0 = *(const u32x4*)(mA + tbase);
    fA1 = *(const u32x4*)(mA + tbase + 32);
    fB0 = *(const u32x4*)(mB + tbase);
    fB1 = *(const u32x4*)(mB + tbase + 32);
  }
  f32x4 Sa[4];
#pragma unroll
  for (int t = 0; t < 4; ++t) Sa[t] = (f32x4){0.f, 0.f, 0.f, 0.f};
  barrier_all();

  for (int c = 0; c < NC; ++c) {
    // ---- phase UV: [U;V] partials, K from regs ----
    {
      f32x4 A0 = {0.f,0.f,0.f,0.f}, A1 = {0.f,0.f,0.f,0.f};
#pragma unroll
      for (int kq = 0; kq < 8; ++kq) {
        int col = kOff + hi * 8 + kq * 32;
        bf16x8 sA = ldf(Sb + lo * DD + (col ^ mLo));
        if (kq & 1) A1 = __builtin_amdgcn_mfma_f32_16x16x32_bf16(sA, bcv(kB[kq]), A1, 0, 0, 0);
        else        A0 = __builtin_amdgcn_mfma_f32_16x16x32_bf16(sA, bcv(kB[kq]), A0, 0, 0, 0);
      }
      f32x4 F = A0 + A1;
      *(f32x4*)&Up[kh][sidx][4 * hi] = F;
    }
    barrier_lgkm();
    // ---- prefetch kB for c+1 (regs free after UV) ----
    if (c + 1 < NC) {
      const u16* src = kb_b + ((size_t)(c + 1) * CC + sidx) * DD;
#pragma unroll
      for (int kq = 0; kq < 8; ++kq)
        kB[kq] = *(const u32x4*)(src + ((kOff + hi * 8 + kq * 32) ^ mS));
    }
    // ---- reduce k-halves; rows m<8 = U, m>=8 = V ----
    f32x4 Fr;
    {
      f32x4 a = *(const f32x4*)&Up[0][sidx][4 * hi];
      f32x4 bq = *(const f32x4*)&Up[1][sidx][4 * hi];
      Fr = a + bq;
      if (kh == 0) {
        if (hi < 2) {
#pragma unroll
          for (int r = 0; r < 4; ++r) {
            int m = 4 * hi + r;
            Ut[m * 64 + (sidx ^ (sx6(m) << 3))] = f2bf(Fr[r]);
          }
        } else {
#pragma unroll
          for (int r = 0; r < 4; ++r) {
            int m = 4 * hi + r - 8;
            Vt[m * 64 + (sidx ^ (sx6(m) << 3))] = f2bf(Fr[r]);
          }
        }
      }
    }
    barrier_lgkm();
    // ---- B (kh0) || C+y (kh1) ----
    {
      bf16x8 vf0 = ldf(Vt + lo * 64 + ((hi * 8) ^ mLo));
      bf16x8 vf1 = ldf(Vt + lo * 64 + ((hi * 8 + 32) ^ mLo));
      bf16x8 uf0 = ldf(Ut + lo * 64 + ((hi * 8) ^ mLo));
      bf16x8 uf1 = ldf(Ut + lo * 64 + ((hi * 8 + 32) ^ mLo));
      if (kh == 0) {
        f32x4 Wa0 = {0.f,0.f,0.f,0.f}, Wa1 = {0.f,0.f,0.f,0.f};
        Wa0 = __builtin_amdgcn_mfma_f32_16x16x32_bf16(vf0, bcv(fA0), Wa0, 0, 0, 0);
        Wa1 = __builtin_amdgcn_mfma_f32_16x16x32_bf16(vf1, bcv(fA1), Wa1, 0, 0, 0);
        Wa0 = __builtin_amdgcn_mfma_f32_16x16x32_bf16(uf0, bcv(fB0), Wa0, 0, 0, 0);
        Wa1 = __builtin_amdgcn_mfma_f32_16x16x32_bf16(uf1, bcv(fB1), Wa1, 0, 0, 0);
        f32x4 Wa = Wa0 + Wa1;
        if (hi < 2) {
#pragma unroll
          for (int r = 0; r < 4; ++r) {
            int v = 4 * hi + r;
            Ws[v * 64 + (sidx ^ (sx6(v) << 3))] = f2bf(Wa[r]);
          }
        }
      } else {
        // bring V (rows m-8 == my v rows) from hi+2 lanes: lane ^ 32
        f32x4 Vsw;
#pragma unroll
        for (int r = 0; r < 4; ++r) Vsw[r] = __shfl_xor(Fr[r], 32, 64);
        f32x4 Oa, Ob = {0.f,0.f,0.f,0.f};
#pragma unroll
        for (int r = 0; r < 4; ++r) Oa[r] = (hi < 2) ? csc * Fr[r] : 0.f;
        Oa = __builtin_amdgcn_mfma_f32_16x16x32_bf16(vf0, bcv(fA0), Oa, 0, 0, 0);
        Ob = __builtin_amdgcn_mfma_f32_16x16x32_bf16(vf1, bcv(fA1), Ob, 0, 0, 0);
        Oa = __builtin_amdgcn_mfma_f32_16x16x32_bf16(uf0, bcv(fB0), Oa, 0, 0, 0);
        Ob = __builtin_amdgcn_mfma_f32_16x16x32_bf16(uf1, bcv(fB1), Ob, 0, 0, 0);
        if (hi < 2) {
          float4 yo = make_float4(Vsw[0] + Oa[0] + Ob[0], Vsw[1] + Oa[1] + Ob[1],
                                  Vsw[2] + Oa[2] + Ob[2], Vsw[3] + Oa[3] + Ob[3]);
          *(float4*)(yb + (size_t)(c * CC + sidx) * DD + v0 + 4 * hi) = yo;
        }
      }
    }
    barrier_lgkm();
    // ---- phase D: S = lam64*S + Ws^T.K ----
    {
      bf16x8 ws0 = ldf(Ws + lo * 64 + ((hi * 8) ^ mLo));
      bf16x8 ws1 = ldf(Ws + lo * 64 + ((hi * 8 + 32) ^ mLo));
#pragma unroll
      for (int t = 0; t < 4; ++t) {
        f32x4 acc = Sa[t] * lam64;
        acc = __builtin_amdgcn_mfma_f32_16x16x32_bf16(ws0, bcv(kt0[t]), acc, 0, 0, 0);
        acc = __builtin_amdgcn_mfma_f32_16x16x32_bf16(ws1, bcv(kt1[t]), acc, 0, 0, 0);
        Sa[t] = acc;
      }
      if (hi < 2) {
#pragma unroll
        for (int t = 0; t < 4; ++t) {
          int kc = 16 * (4 * wid + t) + lo;
#pragma unroll
          for (int r = 0; r < 4; ++r) {
            int v = 4 * hi + r;
            Sb[v * DD + (kc ^ (sx6(v) << 3))] = f2bf(Sa[t][r]);
          }
        }
      }
    }
    // ---- prefetch kt/frames for c+1 ----
    if (c + 1 < NC) {
      const u16* ktc = kbt + (size_t)(b * NC + c + 1) * CC * DD;
#pragma unroll
      for (int t = 0; t < 4; ++t) {
        int k = 16 * (4 * wid + t) + lo;
        const u16* rowp = ktc + (size_t)k * 64;
        int m = sx6(k) << 3;
        kt0[t] = *(const u32x4*)(rowp + ((8 * hi) ^ m));
        kt1[t] = *(const u32x4*)(rowp + ((8 * hi + 32) ^ m));
      }
      size_t tbase = ((size_t)(b * NC + c + 1) * 64 + sidx) * 64 + hi * 8;
      const u16* mA = (kh == 0) ? tbs : p1g;
      const u16* mB = (kh == 0) ? tcs : p2g;
      fA0 = *(const u32x4*)(mA + tbase);
      fA1 = *(const u32x4*)(mA + tbase + 32);
      fB0 = *(const u32x4*)(mB + tbase);
      fB1 = *(const u32x4*)(mB + tbase + 32);
    }
    barrier_lgkm();
  }
}

// ---------------------------------------------------------------------------
// K4: LayerNorm in-place on d_out.
// ---------------------------------------------------------------------------
__global__ __launch_bounds__(256) void k_ln(float* __restrict__ y,
                                            const float* __restrict__ gamma,
                                            const float* __restrict__ lbeta) {
  int row = blockIdx.x * 4 + (threadIdx.x >> 6);
  int lane = threadIdx.x & 63;
  float* yr = y + (size_t)row * DD + lane * 8;
  float4 a = *(const float4*)yr;
  float4 b = *(const float4*)(yr + 4);
  float v[8] = {a.x, a.y, a.z, a.w, b.x, b.y, b.z, b.w};
  float s = 0.f, ss = 0.f;
#pragma unroll
  for (int j = 0; j < 8; ++j) {
    s += v[j];
    ss = fmaf(v[j], v[j], ss);
  }
#pragma unroll
  for (int m = 1; m < 64; m <<= 1) {
    s += __shfl_xor(s, m, 64);
    ss += __shfl_xor(ss, m, 64);
  }
  float mu = s * (1.f / DD);
  float var = ss * (1.f / DD) - mu * mu;
  float inv = rsqrtf(var + EPSF);
  const float* gp = gamma + lane * 8;
  const float* bp = lbeta + lane * 8;
  float4 g0 = *(const float4*)gp;
  float4 g1 = *(const float4*)(gp + 4);
  float4 b0 = *(const float4*)bp;
  float4 b1 = *(const float4*)(bp + 4);
  float g[8] = {g0.x, g0.y, g0.z, g0.w, g1.x, g1.y, g1.z, g1.w};
  float bb[8] = {b0.x, b0.y, b0.z, b0.w, b1.x, b1.y, b1.z, b1.w};
#pragma unroll
  for (int j = 0; j < 8; ++j) v[j] = (v[j] - mu) * inv * g[j] + bb[j];
  *(float4*)yr = make_float4(v[0], v[1], v[2], v[3]);
  *(float4*)(yr + 4) = make_float4(v[4], v[5], v[6], v[7]);
}

// ---------------------------------------------------------------------------
extern "C" void kernel_launch(void* const* d_in, const int* in_sizes, int n_in,
                              void* d_out, int out_size, void* d_ws, size_t ws_size,
                              hipStream_t stream) {
  const float* x     = (const float*)d_in[0];
  const float* W     = (const float*)d_in[1];
  const float* eta   = (const float*)d_in[2];
  const float* ll    = (const float*)d_in[3];
  const float* gamma = (const float*)d_in[4];
  const float* lbeta = (const float*)d_in[5];
  float* out = (float*)d_out;

  // ws (u16): kbs 8MB | kbt 8MB | wbb 0.5MB | tbs/tcs/p1/p2 1MB each (~20.5MB)
  u16* kbs = (u16*)d_ws;
  u16* kbt = kbs + (size_t)BB * LL * DD;
  u16* wbb = kbt + (size_t)BB * LL * DD;
  u16* tbs = wbb + (size_t)DD * DD;
  u16* tcs = tbs + (size_t)BB * NC * 64 * 64;
  u16* p1g = tcs + (size_t)BB * NC * 64 * 64;
  u16* p2g = p1g + (size_t)BB * NC * 64 * 64;

  k_cvtW<<<128, 256, 0, stream>>>(W, wbb);
  k_prep3<<<BB * NC, 256, 0, stream>>>(x, eta, ll, kbs, tbs, tcs, p1g, p2g, kbt);
  k_scan9<<<256, 512, 0, stream>>>(kbs, kbt, wbb, tbs, tcs, p1g, p2g, ll, out);
  k_ln<<<2048, 256, 0, stream>>>(out, gamma, lbeta);
}